// Round 14
// baseline (2329.305 us; speedup 1.0000x reference)
//
#include <hip/hip_runtime.h>

typedef __bf16 bhalf;
typedef __bf16 bh8_t __attribute__((ext_vector_type(8)));
typedef float f4_t __attribute__((ext_vector_type(4)));

#define MFMA16(A, B, C) __builtin_amdgcn_mfma_f32_16x16x32_bf16((A), (B), (C), 0, 0, 0)

// Problem: B=32768, D_IN=128, H=1024, N_FLUX=512, N_MET=256, N_IN=128
//
// ROUND 14: direct-to-register B streaming. r13's staging was wave-local ->
// G/P/Pt need no LDS at all. B-fragments now load straight to VGPRs (plain
// global loads, compiler waitcnt, 2-deep named-register rotation). Deletes:
// LDS staging writes (640 KB/iter), B-fragment ds_reads, all manual vmcnt +
// per-step barriers. LDS shrinks to 64 KB (hid[32][1024] XOR-swizzled) ->
// 2 blocks/CU possible. Only V (shared A-operand) + R stay in LDS; 3
// __syncthreads()/iter. Register budget ~115: G-phase = 2 passes x 2 n-tiles
// (dacc 16/pass), Pt prefetch at half-chunk granularity, rotation buffers
// named (runtime-indexed arrays would spill - rule #20).

#define OFF_W1T  0
#define OFF_W2T  (OFF_W1T + 1024 * 128)
#define OFF_PINB (OFF_W2T + 512 * 1024)
#define OFF_PT   (OFF_PINB + 128 * 512)
#define OFF_G    (OFF_PT + 512 * 128)

__global__ __launch_bounds__(256) void amn_prep(
    const float* __restrict__ W1, const float* __restrict__ W2,
    const float* __restrict__ Pin, bhalf* __restrict__ ws) {
  unsigned i = blockIdx.x * 256u + threadIdx.x;
  if (i < 131072u) {                   // W1t[n][k] = W1[k][n]
    unsigned n = i >> 7, k = i & 127u;
    ws[OFF_W1T + i] = (bhalf)W1[k * 1024u + n];
  } else if (i < 655360u) {            // W2t[n][k] = W2[k][n]
    unsigned j = i - 131072u;
    unsigned n = j >> 10, k = j & 1023u;
    ws[OFF_W2T + j] = (bhalf)W2[k * 512u + n];
  } else if (i < 720896u) {            // Pinb = bf16(Pin)
    unsigned j = i - 655360u;
    ws[OFF_PINB + j] = (bhalf)Pin[j];
  } else if (i < 786432u) {            // Pt[n][k] = Pin[k][n] * 2/128
    unsigned j = i - 720896u;
    unsigned n = j >> 7, k = j & 127u;
    ws[OFF_PT + j] = (bhalf)(Pin[k * 512u + n] * 0.015625f);
  }
}

// G[i][j] = (2/256) * sum_k S[k][i]*S[k][j]
__global__ __launch_bounds__(256) void amn_gram(
    const float* __restrict__ S, bhalf* __restrict__ ws) {
  const unsigned bi = blockIdx.x >> 5, bj = blockIdx.x & 31u;
  __shared__ float SA[256][16];
  __shared__ float SB[256][16];
  const unsigned t = threadIdx.x;
#pragma unroll
  for (int p = 0; p < 16; ++p) {
    unsigned e = p * 256u + t;
    unsigned k = e >> 4, c = e & 15u;
    SA[k][c] = S[k * 512u + bi * 16u + c];
    SB[k][c] = S[k * 512u + bj * 16u + c];
  }
  __syncthreads();
  const unsigned ti = t >> 4, tj = t & 15u;
  float acc = 0.f;
#pragma unroll 8
  for (int k = 0; k < 256; ++k) acc += SA[k][ti] * SB[k][tj];
  ws[OFF_G + (bi * 16u + ti) * 512u + bj * 16u + tj] = (bhalf)(acc * 0.0078125f);
}

__device__ inline bh8_t cvt8(f4_t f0, f4_t f1) {
  bh8_t r;
  r[0] = (bhalf)f0[0]; r[1] = (bhalf)f0[1]; r[2] = (bhalf)f0[2]; r[3] = (bhalf)f0[3];
  r[4] = (bhalf)f1[0]; r[5] = (bhalf)f1[1]; r[6] = (bhalf)f1[2]; r[7] = (bhalf)f1[3];
  return r;
}
__device__ inline unsigned pk2(float a, float b) {
  union { bhalf h; unsigned short s; } x, y;
  x.h = (bhalf)a; y.h = (bhalf)b;
  return (unsigned)x.s | ((unsigned)y.s << 16);
}
__device__ inline float up_lo(unsigned u) {
  union { unsigned u; float f; } t; t.u = u << 16; return t.f;
}
__device__ inline float up_hi(unsigned u) {
  union { unsigned u; float f; } t; t.u = u & 0xffff0000u; return t.f;
}

// LDS (65,536 B total -> 2 blocks/CU candidate):
//   hid [32 rows][128 slots x 16B], slot ^= row&7  @ 0   (65,536; MLP only)
//   V   [32][520] bf16 linear                      @ 0   (33,280; loop)
//   R   [32][128] bf16 col-rotated                 @ 33280 (8,192; loop)
#define RBASE 33280u
#define SMEM_BYTES 65536

__global__ __launch_bounds__(512) void amn_main(
    const float* __restrict__ input, const float* __restrict__ Vin,
    const float* __restrict__ b1, const float* __restrict__ b2,
    const int* __restrict__ niter_p,
    const bhalf* __restrict__ ws, float* __restrict__ out) {

  const unsigned tid = threadIdx.x;
  const unsigned w  = tid >> 6;    // wave 0..7
  const unsigned l  = tid & 63u;
  const unsigned lq = l >> 4;      // 0..3
  const unsigned lr = l & 15u;     // 0..15
  const unsigned row0 = blockIdx.x * 32u;

  const bhalf* W1t = ws + OFF_W1T;
  const bhalf* W2t = ws + OFF_W2T;

  __shared__ __align__(16) unsigned char smem[SMEM_BYTES];
  bhalf* V_lds = (bhalf*)smem;               // [32][520]
  bhalf* R_lds = (bhalf*)(smem + RBASE);     // [32][128] rotated

  // ===== MLP1: hidden = relu(input @ W1 + b1); wave w owns tiles 8w..8w+7 =====
  // hid(row, col) at byte row*2048 + ((slot ^ (row&7))*16 + (col&7)*2), slot=col>>3
  {
    f4_t hacc[2][8];
#pragma unroll
    for (int mt = 0; mt < 2; ++mt)
#pragma unroll
      for (int t = 0; t < 8; ++t) hacc[mt][t] = (f4_t)0.f;

#pragma unroll
    for (int k = 0; k < 4; ++k) {   // K = 128
      bh8_t a[2];
#pragma unroll
      for (int mt = 0; mt < 2; ++mt) {
        const float* ap = input + (row0 + 16u * mt + lr) * 128u + k * 32 + lq * 8u;
        a[mt] = cvt8(*(const f4_t*)ap, *(const f4_t*)(ap + 4));
      }
#pragma unroll
      for (int t = 0; t < 8; ++t) {
        bh8_t b = *(const bh8_t*)(W1t + (16u * (8u * w + t) + lr) * 128u + k * 32 + lq * 8u);
#pragma unroll
        for (int mt = 0; mt < 2; ++mt) hacc[mt][t] = MFMA16(a[mt], b, hacc[mt][t]);
      }
    }
#pragma unroll
    for (int t = 0; t < 8; ++t) {
      unsigned col = 16u * (8u * w + t) + lr;
      unsigned slot = col >> 3, win = (col & 7u) * 2u;
      float bias = b1[col];
#pragma unroll
      for (int mt = 0; mt < 2; ++mt)
#pragma unroll
        for (int r = 0; r < 4; ++r) {
          unsigned row = 16u * mt + 4u * lq + r;
          *(bhalf*)(smem + row * 2048u + ((slot ^ (row & 7u)) << 4) + win) =
              (bhalf)fmaxf(hacc[mt][t][r] + bias, 0.f);
        }
    }
  }
  __syncthreads();

  // ===== MLP2: V0 = hidden @ W2 + b2; wave w owns V n-tiles 4w..4w+3 =====
  f4_t Vreg[2][4];
#pragma unroll
  for (int mt = 0; mt < 2; ++mt)
#pragma unroll
    for (int n = 0; n < 4; ++n) Vreg[mt][n] = (f4_t)0.f;

#pragma unroll 2
  for (int k = 0; k < 32; ++k) {  // K = 1024
    bh8_t a[2];
#pragma unroll
    for (int mt = 0; mt < 2; ++mt) {
      unsigned row = 16u * mt + lr;
      a[mt] = *(const bh8_t*)(smem + row * 2048u +
                              (((4u * (unsigned)k + lq) ^ (row & 7u)) << 4));
    }
#pragma unroll
    for (int n = 0; n < 4; ++n) {
      bh8_t b = *(const bh8_t*)(W2t + (16u * (4u * w + n) + lr) * 1024u + k * 32 + lq * 8u);
#pragma unroll
      for (int mt = 0; mt < 2; ++mt) Vreg[mt][n] = MFMA16(a[mt], b, Vreg[mt][n]);
    }
  }
#pragma unroll
  for (int n = 0; n < 4; ++n) {
    float bias = b2[16u * (4u * w + n) + lr];
#pragma unroll
    for (int mt = 0; mt < 2; ++mt)
#pragma unroll
      for (int r = 0; r < 4; ++r) Vreg[mt][n][r] += bias;
  }

  // ---- Vin for u-tile w, packed bf16 ----
  unsigned Vinpk[2][2];
#pragma unroll
  for (int mt = 0; mt < 2; ++mt) {
    float vi[4];
#pragma unroll
    for (int r = 0; r < 4; ++r)
      vi[r] = Vin[(row0 + 16u * mt + 4u * lq + r) * 128u + 16u * w + lr];
    Vinpk[mt][0] = pk2(vi[0], vi[1]);
    Vinpk[mt][1] = pk2(vi[2], vi[3]);
  }

  unsigned Dpk[2][4][2];
#pragma unroll
  for (int mt = 0; mt < 2; ++mt)
#pragma unroll
    for (int n = 0; n < 4; ++n) { Dpk[mt][n][0] = 0u; Dpk[mt][n][1] = 0u; }

  // wave-local global byte-pointers (per-lane fragment bases)
  const char* g0p = (const char*)(ws + OFF_G) + (16u * (4u * w + 0u) + lr) * 1024u + lq * 16u;
  const char* g1p = (const char*)(ws + OFF_G) + (16u * (4u * w + 1u) + lr) * 1024u + lq * 16u;
  const char* g2p = (const char*)(ws + OFF_G) + (16u * (4u * w + 2u) + lr) * 1024u + lq * 16u;
  const char* g3p = (const char*)(ws + OFF_G) + (16u * (4u * w + 3u) + lr) * 1024u + lq * 16u;
  const char* pp  = (const char*)(ws + OFF_PINB) + (16u * w + lr) * 1024u + lq * 16u;
  const char* pt0 = (const char*)(ws + OFF_PT) + (16u * (4u * w + 0u) + lr) * 256u + lq * 16u;
  const char* pt1 = (const char*)(ws + OFF_PT) + (16u * (4u * w + 1u) + lr) * 256u + lq * 16u;
  const char* pt2 = (const char*)(ws + OFF_PT) + (16u * (4u * w + 2u) + lr) * 256u + lq * 16u;
  const char* pt3 = (const char*)(ws + OFF_PT) + (16u * (4u * w + 3u) + lr) * 256u + lq * 16u;

  const int niter = niter_p[0];

  __syncthreads();  // hid reads done; V/R regions reusable

  // ---- stage V0 (bf16, linear 520) ----
#pragma unroll
  for (int mt = 0; mt < 2; ++mt)
#pragma unroll
    for (int n = 0; n < 4; ++n) {
      unsigned col = 16u * (4u * w + n) + lr;
#pragma unroll
      for (int r = 0; r < 4; ++r)
        V_lds[(16u * mt + 4u * lq + r) * 520u + col] = (bhalf)Vreg[mt][n][r];
    }
  __syncthreads();  // BAR_B(0): V0 visible

  // ================= momentum iterations =================
  for (int it = 0; it < niter; ++it) {
    f4_t dacc[4][2];
#pragma unroll
    for (int nt = 0; nt < 4; ++nt) { dacc[nt][0] = (f4_t)0.f; dacc[nt][1] = (f4_t)0.f; }

    // ======== pass A: n-tiles 4w,4w+1 (G segs 0,1) + Uacc (P seg w) ========
    {
      f4_t Uacc[2];
      Uacc[0] = (f4_t)0.f; Uacc[1] = (f4_t)0.f;
      // 2-deep rotation, named stages (chunk t in X, t+1 in Y)
      bh8_t gX0 = *(const bh8_t*)(g0p);
      bh8_t gX1 = *(const bh8_t*)(g1p);
      bh8_t pX  = *(const bh8_t*)(pp);
      bh8_t gY0 = *(const bh8_t*)(g0p + 64);
      bh8_t gY1 = *(const bh8_t*)(g1p + 64);
      bh8_t pY  = *(const bh8_t*)(pp + 64);
#pragma unroll 1
      for (int t = 0; t < 16; t += 2) {
        {
          bh8_t a0 = *(const bh8_t*)(V_lds + lr * 520u + t * 32 + lq * 8u);
          bh8_t a1 = *(const bh8_t*)(V_lds + (16u + lr) * 520u + t * 32 + lq * 8u);
          dacc[0][0] = MFMA16(a0, gX0, dacc[0][0]);
          dacc[0][1] = MFMA16(a1, gX0, dacc[0][1]);
          dacc[1][0] = MFMA16(a0, gX1, dacc[1][0]);
          dacc[1][1] = MFMA16(a1, gX1, dacc[1][1]);
          Uacc[0] = MFMA16(a0, pX, Uacc[0]);
          Uacc[1] = MFMA16(a1, pX, Uacc[1]);
          if (t + 2 < 16) {
            gX0 = *(const bh8_t*)(g0p + (t + 2) * 64);
            gX1 = *(const bh8_t*)(g1p + (t + 2) * 64);
            pX  = *(const bh8_t*)(pp + (t + 2) * 64);
          }
        }
        {
          bh8_t a0 = *(const bh8_t*)(V_lds + lr * 520u + (t + 1) * 32 + lq * 8u);
          bh8_t a1 = *(const bh8_t*)(V_lds + (16u + lr) * 520u + (t + 1) * 32 + lq * 8u);
          dacc[0][0] = MFMA16(a0, gY0, dacc[0][0]);
          dacc[0][1] = MFMA16(a1, gY0, dacc[0][1]);
          dacc[1][0] = MFMA16(a0, gY1, dacc[1][0]);
          dacc[1][1] = MFMA16(a1, gY1, dacc[1][1]);
          Uacc[0] = MFMA16(a0, pY, Uacc[0]);
          Uacc[1] = MFMA16(a1, pY, Uacc[1]);
          if (t + 3 < 16) {
            gY0 = *(const bh8_t*)(g0p + (t + 3) * 64);
            gY1 = *(const bh8_t*)(g1p + (t + 3) * 64);
            pY  = *(const bh8_t*)(pp + (t + 3) * 64);
          }
        }
      }
      // R = relu(U - Vin), col-rotated: (row,col) at row*128 + ((col+8row)&127)
#pragma unroll
      for (int mt = 0; mt < 2; ++mt) {
        float rv[4] = { fmaxf(Uacc[mt][0] - up_lo(Vinpk[mt][0]), 0.f),
                        fmaxf(Uacc[mt][1] - up_hi(Vinpk[mt][0]), 0.f),
                        fmaxf(Uacc[mt][2] - up_lo(Vinpk[mt][1]), 0.f),
                        fmaxf(Uacc[mt][3] - up_hi(Vinpk[mt][1]), 0.f) };
        unsigned col = 16u * w + lr;
#pragma unroll
        for (int r = 0; r < 4; ++r) {
          unsigned row = 16u * mt + 4u * lq + r;
          R_lds[row * 128u + ((col + 8u * row) & 127u)] = (bhalf)rv[r];
        }
      }
    }
    __syncthreads();   // BAR_C: R visible

    // ======== pass B: n-tiles 4w+2,4w+3 (G segs 2,3) ========
    {
      bh8_t gX2 = *(const bh8_t*)(g2p);
      bh8_t gX3 = *(const bh8_t*)(g3p);
      bh8_t gY2 = *(const bh8_t*)(g2p + 64);
      bh8_t gY3 = *(const bh8_t*)(g3p + 64);
#pragma unroll 1
      for (int t = 0; t < 16; t += 2) {
        {
          bh8_t a0 = *(const bh8_t*)(V_lds + lr * 520u + t * 32 + lq * 8u);
          bh8_t a1 = *(const bh8_t*)(V_lds + (16u + lr) * 520u + t * 32 + lq * 8u);
          dacc[2][0] = MFMA16(a0, gX2, dacc[2][0]);
          dacc[2][1] = MFMA16(a1, gX2, dacc[2][1]);
          dacc[3][0] = MFMA16(a0, gX3, dacc[3][0]);
          dacc[3][1] = MFMA16(a1, gX3, dacc[3][1]);
          if (t + 2 < 16) {
            gX2 = *(const bh8_t*)(g2p + (t + 2) * 64);
            gX3 = *(const bh8_t*)(g3p + (t + 2) * 64);
          }
        }
        {
          bh8_t a0 = *(const bh8_t*)(V_lds + lr * 520u + (t + 1) * 32 + lq * 8u);
          bh8_t a1 = *(const bh8_t*)(V_lds + (16u + lr) * 520u + (t + 1) * 32 + lq * 8u);
          dacc[2][0] = MFMA16(a0, gY2, dacc[2][0]);
          dacc[2][1] = MFMA16(a1, gY2, dacc[2][1]);
          dacc[3][0] = MFMA16(a0, gY3, dacc[3][0]);
          dacc[3][1] = MFMA16(a1, gY3, dacc[3][1]);
          if (t + 3 < 16) {
            gY2 = *(const bh8_t*)(g2p + (t + 3) * 64);
            gY3 = *(const bh8_t*)(g3p + (t + 3) * 64);
          }
        }
      }
    }

    // ======== Pt phase: dacc += R @ Pt, 4 chunks x 2 half-steps ========
    {
      // half-step s: c=s>>1, h=s&1, segs {2h, 2h+1}; 2-frag rotation
      bh8_t fX0 = *(const bh8_t*)(pt0);          // s=0: c0,h0
      bh8_t fX1 = *(const bh8_t*)(pt1);
      bh8_t fY0 = *(const bh8_t*)(pt2);          // s=1: c0,h1
      bh8_t fY1 = *(const bh8_t*)(pt3);
#pragma unroll
      for (int c = 0; c < 4; ++c) {
        unsigned ro = ((unsigned)c * 32u + lq * 8u + 8u * lr) & 127u;
        bh8_t a0 = *(const bh8_t*)(R_lds + lr * 128u + ro);
        unsigned ro1 = ((unsigned)c * 32u + lq * 8u + 8u * (16u + lr)) & 127u;
        bh8_t a1 = *(const bh8_t*)(R_lds + (16u + lr) * 128u + ro1);
        // h=0 (segs 0,1) from X
        dacc[0][0] = MFMA16(a0, fX0, dacc[0][0]);
        dacc[0][1] = MFMA16(a1, fX0, dacc[0][1]);
        dacc[1][0] = MFMA16(a0, fX1, dacc[1][0]);
        dacc[1][1] = MFMA16(a1, fX1, dacc[1][1]);
        if (c + 1 < 4) {            // prefetch (c+1, h0) into X
          fX0 = *(const bh8_t*)(pt0 + (c + 1) * 64);
          fX1 = *(const bh8_t*)(pt1 + (c + 1) * 64);
        }
        // h=1 (segs 2,3) from Y
        dacc[2][0] = MFMA16(a0, fY0, dacc[2][0]);
        dacc[2][1] = MFMA16(a1, fY0, dacc[2][1]);
        dacc[3][0] = MFMA16(a0, fY1, dacc[3][0]);
        dacc[3][1] = MFMA16(a1, fY1, dacc[3][1]);
        if (c + 1 < 4) {            // prefetch (c+1, h1) into Y
          fY0 = *(const bh8_t*)(pt2 + (c + 1) * 64);
          fY1 = *(const bh8_t*)(pt3 + (c + 1) * 64);
        }
      }
    }

    // ---- momentum update: dV += min(V,0)*2/512; d = .9d - .01dV; V += d ----
#pragma unroll
    for (int nt = 0; nt < 4; ++nt)
#pragma unroll
      for (int mt = 0; mt < 2; ++mt) {
        float dv0 = dacc[nt][mt][0] + fminf(Vreg[mt][nt][0], 0.f) * 0.00390625f;
        float dv1 = dacc[nt][mt][1] + fminf(Vreg[mt][nt][1], 0.f) * 0.00390625f;
        float dv2 = dacc[nt][mt][2] + fminf(Vreg[mt][nt][2], 0.f) * 0.00390625f;
        float dv3 = dacc[nt][mt][3] + fminf(Vreg[mt][nt][3], 0.f) * 0.00390625f;
        float d0 = 0.9f * up_lo(Dpk[mt][nt][0]) - 0.01f * dv0;
        float d1 = 0.9f * up_hi(Dpk[mt][nt][0]) - 0.01f * dv1;
        float d2 = 0.9f * up_lo(Dpk[mt][nt][1]) - 0.01f * dv2;
        float d3 = 0.9f * up_hi(Dpk[mt][nt][1]) - 0.01f * dv3;
        Vreg[mt][nt][0] += d0; Vreg[mt][nt][1] += d1;
        Vreg[mt][nt][2] += d2; Vreg[mt][nt][3] += d3;
        Dpk[mt][nt][0] = pk2(d0, d1);
        Dpk[mt][nt][1] = pk2(d2, d3);
      }

    __syncthreads();   // BAR_A: all V/R reads of iter it complete

    // ---- stage V(it+1) ----
#pragma unroll
    for (int mt = 0; mt < 2; ++mt)
#pragma unroll
      for (int n = 0; n < 4; ++n) {
        unsigned col = 16u * (4u * w + n) + lr;
#pragma unroll
        for (int r = 0; r < 4; ++r)
          V_lds[(16u * mt + 4u * lq + r) * 520u + col] = (bhalf)Vreg[mt][n][r];
      }
    __syncthreads();   // BAR_B: V(it+1) visible
  }

  // ---- write final V ----
#pragma unroll
  for (int mt = 0; mt < 2; ++mt)
#pragma unroll
    for (int n = 0; n < 4; ++n) {
      unsigned col = 16u * (4u * w + n) + lr;
#pragma unroll
      for (int r = 0; r < 4; ++r)
        out[(row0 + 16u * mt + 4u * lq + r) * 512u + col] = Vreg[mt][n][r];
    }
}

extern "C" void kernel_launch(void* const* d_in, const int* in_sizes, int n_in,
                              void* d_out, int out_size, void* d_ws, size_t ws_size,
                              hipStream_t stream) {
  const float* input = (const float*)d_in[0];
  // d_in[1] = Vref (unused by reference)
  const float* Vin = (const float*)d_in[2];
  const float* W1  = (const float*)d_in[3];
  const float* b1  = (const float*)d_in[4];
  const float* W2  = (const float*)d_in[5];
  const float* b2  = (const float*)d_in[6];
  const float* S   = (const float*)d_in[7];
  const float* Pin = (const float*)d_in[8];
  const int* nit   = (const int*)d_in[9];
  bhalf* ws  = (bhalf*)d_ws;
  float* out = (float*)d_out;

  amn_prep<<<3072, 256, 0, stream>>>(W1, W2, Pin, ws);
  amn_gram<<<1024, 256, 0, stream>>>(S, ws);
  amn_main<<<1024, 512, 0, stream>>>(input, Vin, b1, b2, nit, ws, out);
}